// Round 16
// baseline (281.829 us; speedup 1.0000x reference)
//
#include <hip/hip_runtime.h>
#include <stdint.h>

#define NROWS 16384
#define DIM 512
#define CSPLIT 8
#define COLS_PER_SPLIT (NROWS / CSPLIT)   // 2048
#define BM 256                            // rows per block (4 waves x 64)
#define NT 64                             // cols per tile
#define BK 128                            // k per K-step
#define NTILES (COLS_PER_SPLIT / NT)      // 32
#define PPT (DIM / BK)                    // 4 K-steps per tile
#define NPHASE (NTILES * PPT)             // 128
#define PMASK (NPHASE - 1)

using i32x4 = __attribute__((ext_vector_type(4))) int;
using char8 = __attribute__((ext_vector_type(8))) signed char;

#define AS1 __attribute__((address_space(1)))
#define AS3 __attribute__((address_space(3)))

// ---------------- Kernel A: L2-normalize + FIXED-scale i8 quantize ----------
__global__ __launch_bounds__(256) void knorm(const float* __restrict__ in,
                                             signed char* __restrict__ xq,
                                             float* __restrict__ inv) {
  const int lane = threadIdx.x & 63;
  const int wave = threadIdx.x >> 6;
  const int row = blockIdx.x * 4 + wave;
  const float4* p = (const float4*)(in + (size_t)row * DIM + lane * 8);
  const float4 a = p[0], b = p[1];
  float ss = a.x*a.x + a.y*a.y + a.z*a.z + a.w*a.w
           + b.x*b.x + b.y*b.y + b.z*b.z + b.w*b.w;
  #pragma unroll
  for (int m = 32; m >= 1; m >>= 1) ss += __shfl_xor(ss, m, 64);
  const float iv = 1.0f / fmaxf(sqrtf(ss), 1e-8f);
  const float s508 = iv * 508.0f;
  char8 q;
  q[0] = (signed char)(int)rintf(fminf(fmaxf(a.x * s508, -127.f), 127.f));
  q[1] = (signed char)(int)rintf(fminf(fmaxf(a.y * s508, -127.f), 127.f));
  q[2] = (signed char)(int)rintf(fminf(fmaxf(a.z * s508, -127.f), 127.f));
  q[3] = (signed char)(int)rintf(fminf(fmaxf(a.w * s508, -127.f), 127.f));
  q[4] = (signed char)(int)rintf(fminf(fmaxf(b.x * s508, -127.f), 127.f));
  q[5] = (signed char)(int)rintf(fminf(fmaxf(b.y * s508, -127.f), 127.f));
  q[6] = (signed char)(int)rintf(fminf(fmaxf(b.z * s508, -127.f), 127.f));
  q[7] = (signed char)(int)rintf(fminf(fmaxf(b.w * s508, -127.f), 127.f));
  *(char8*)(xq + (size_t)row * DIM + lane * 8) = q;
  if (lane == 0) inv[row] = iv;
}

// ---------------- Kernel B: i8 Gram + fused integer argmax ------------------
// R10 + CROSS-K-STEP register prefetch: counted vmcnt(2) (phase kb+1 landed),
// and each step issues the NEXT step's 8 ds_reads (into the alternate fa/fb
// set) before its own 32 MFMAs — LDS stream hides under the matrix stream;
// in-order lgkm means current frags are ready with lgkmcnt(8), no exposed
// read latency after the barrier.
__global__ __launch_bounds__(256, 2) void kdots(const signed char* __restrict__ xq,
                                                uint32_t* __restrict__ keys) {
  const int tid  = threadIdx.x;
  const int lane = tid & 63;
  const int wave = tid >> 6;
  const int bx = blockIdx.x;
  const int cs = bx & (CSPLIT - 1);     // same-cs blocks land on same XCD (%8)
  const int rb = bx >> 3;
  const int rowbase  = rb * BM + wave * 64;
  const int colsplit = cs * COLS_PER_SPLIT;
  const int tdiag = ((rowbase >> 11) == cs) ? ((rowbase - colsplit) >> 6) : -1;
  const int c15 = lane & 15;
  const int hi4 = (lane >> 4) * 4;

  __shared__ signed char lds[4][NT * BK];   // 4 x 8 KB

  // ---- A fragments in registers: 4 rowfrags x 8 kfrags(K=64) = 128 VGPR ----
  i32x4 areg[4][8];
  #pragma unroll
  for (int rf = 0; rf < 4; ++rf) {
    const signed char* ap =
        xq + (size_t)(rowbase + rf * 16 + c15) * DIM + ((lane >> 4) * 16);
    #pragma unroll
    for (int kf = 0; kf < 8; ++kf)
      areg[rf][kf] = *(const i32x4*)(ap + kf * 64);
  }

  uint32_t rkey[4][4];
  #pragma unroll
  for (int rf = 0; rf < 4; ++rf)
    #pragma unroll
    for (int r = 0; r < 4; ++r) rkey[rf][r] = 0u;

  i32x4 acc[4][4];   // zero-C first K-step writes; EPI reads next tile

  // stage one 8 KB buffer: 2 global_load_lds(16B) per thread.
  auto STAGE = [&](int buf, int p) {
    const int tt = p >> 2, kb2 = p & 3;
    #pragma unroll
    for (int h = 0; h < 2; ++h) {
      const int u = h * 256 + tid;
      const int col = u >> 3;
      const int k16 = u & 7;
      const signed char* g = xq + (size_t)(colsplit + tt * NT + col) * DIM
                           + kb2 * BK + ((k16 ^ (col & 7)) << 4);
      char* l = ((char*)&lds[buf][0]) + u * 16;
      __builtin_amdgcn_global_load_lds((AS1 const void*)g, (AS3 void*)l, 16, 0, 0);
    }
  };

  const int ro0 = c15 * 128 + (((lane >> 4) ^ (lane & 7)) << 4);
  const int ro1 = ro0 ^ 64;

  // two frag sets (8 x i32x4 each), kb-parity double buffer
  i32x4 fa0, fa1, fa2, fa3, fa4, fa5, fa6, fa7;
  i32x4 fb0, fb1, fb2, fb3, fb4, fb5, fb6, fb7;

#define PREF(P, BASE)                                                          \
  P##0 = *(const i32x4*)((BASE) + ro0);                                        \
  P##1 = *(const i32x4*)((BASE) + ro1);                                        \
  P##2 = *(const i32x4*)((BASE) + 2048 + ro0);                                 \
  P##3 = *(const i32x4*)((BASE) + 2048 + ro1);                                 \
  P##4 = *(const i32x4*)((BASE) + 4096 + ro0);                                 \
  P##5 = *(const i32x4*)((BASE) + 4096 + ro1);                                 \
  P##6 = *(const i32x4*)((BASE) + 6144 + ro0);                                 \
  P##7 = *(const i32x4*)((BASE) + 6144 + ro1);

#define EPI(Q, COLB0P, DG)                                                     \
  do {                                                                         \
    const uint32_t k0c =                                                       \
        0x80000000u + 2047u - (uint32_t)((COLB0P) + (Q) * 16 + c15);           \
    _Pragma("unroll")                                                          \
    for (int rf = 0; rf < 4; ++rf) {                                           \
      _Pragma("unroll")                                                        \
      for (int r = 0; r < 4; ++r) {                                            \
        const int t1 = acc[rf][Q][r] >> 3;                                     \
        uint32_t key = ((uint32_t)t1 << 11) + k0c;                             \
        if (rf == (Q) && (DG)) key = (c15 == hi4 + r) ? 0u : key;              \
        rkey[rf][r] = rkey[rf][r] > key ? rkey[rf][r] : key;                   \
      }                                                                        \
    }                                                                          \
  } while (0)

#define CLUSTER(KB, Q, BA, BB)                                                 \
  __builtin_amdgcn_s_setprio(1);                                              \
  acc[0][Q] = __builtin_amdgcn_mfma_i32_16x16x64_i8(areg[0][(KB)*2], BA, acc[0][Q], 0,0,0);\
  acc[1][Q] = __builtin_amdgcn_mfma_i32_16x16x64_i8(areg[1][(KB)*2], BA, acc[1][Q], 0,0,0);\
  acc[2][Q] = __builtin_amdgcn_mfma_i32_16x16x64_i8(areg[2][(KB)*2], BA, acc[2][Q], 0,0,0);\
  acc[3][Q] = __builtin_amdgcn_mfma_i32_16x16x64_i8(areg[3][(KB)*2], BA, acc[3][Q], 0,0,0);\
  acc[0][Q] = __builtin_amdgcn_mfma_i32_16x16x64_i8(areg[0][(KB)*2+1], BB, acc[0][Q], 0,0,0);\
  acc[1][Q] = __builtin_amdgcn_mfma_i32_16x16x64_i8(areg[1][(KB)*2+1], BB, acc[1][Q], 0,0,0);\
  acc[2][Q] = __builtin_amdgcn_mfma_i32_16x16x64_i8(areg[2][(KB)*2+1], BB, acc[2][Q], 0,0,0);\
  acc[3][Q] = __builtin_amdgcn_mfma_i32_16x16x64_i8(areg[3][(KB)*2+1], BB, acc[3][Q], 0,0,0);\
  __builtin_amdgcn_s_setprio(0);

#define CLUSTERZ(Q, BA, BB)                                                    \
  __builtin_amdgcn_s_setprio(1);                                              \
  acc[0][Q] = __builtin_amdgcn_mfma_i32_16x16x64_i8(areg[0][0], BA, (i32x4){0,0,0,0}, 0,0,0);\
  acc[1][Q] = __builtin_amdgcn_mfma_i32_16x16x64_i8(areg[1][0], BA, (i32x4){0,0,0,0}, 0,0,0);\
  acc[2][Q] = __builtin_amdgcn_mfma_i32_16x16x64_i8(areg[2][0], BA, (i32x4){0,0,0,0}, 0,0,0);\
  acc[3][Q] = __builtin_amdgcn_mfma_i32_16x16x64_i8(areg[3][0], BA, (i32x4){0,0,0,0}, 0,0,0);\
  acc[0][Q] = __builtin_amdgcn_mfma_i32_16x16x64_i8(areg[0][1], BB, acc[0][Q], 0,0,0);\
  acc[1][Q] = __builtin_amdgcn_mfma_i32_16x16x64_i8(areg[1][1], BB, acc[1][Q], 0,0,0);\
  acc[2][Q] = __builtin_amdgcn_mfma_i32_16x16x64_i8(areg[2][1], BB, acc[2][Q], 0,0,0);\
  acc[3][Q] = __builtin_amdgcn_mfma_i32_16x16x64_i8(areg[3][1], BB, acc[3][Q], 0,0,0);\
  __builtin_amdgcn_s_setprio(0);

#define WAITB                                                                  \
  asm volatile("s_waitcnt vmcnt(2)" ::: "memory");                             \
  __builtin_amdgcn_s_barrier();                                                \
  asm volatile("" ::: "memory");

  __syncthreads();   // drains areg loads (vmcnt -> 0)
  STAGE(0, 0); STAGE(1, 1); STAGE(2, 2);   // depth-3 prologue: 6 outstanding
  asm volatile("s_waitcnt vmcnt(4)" ::: "memory");   // phase 0 landed
  PREF(fa, (const char*)&lds[0][0])        // K-step 0's frags

  for (int t = 0; t < NTILES; ++t) {
    const int colb0p = (t - 1) * NT;
    const bool dg = ((t - 1) == tdiag);
    // ---- kb=0: uses fa; prefetch fb <- buf1 (phase landed via vmcnt(2)) ----
    WAITB
    STAGE(3, (t * PPT + 3) & PMASK);
    PREF(fb, (const char*)&lds[1][0])
    if (t) EPI(0, colb0p, dg);
    CLUSTERZ(0, fa0, fa1)
    if (t) EPI(1, colb0p, dg);
    CLUSTERZ(1, fa2, fa3)
    if (t) EPI(2, colb0p, dg);
    CLUSTERZ(2, fa4, fa5)
    if (t) EPI(3, colb0p, dg);
    CLUSTERZ(3, fa6, fa7)
    // ---- kb=1: uses fb; prefetch fa <- buf2 ----
    WAITB
    STAGE(0, (t * PPT + 4) & PMASK);
    PREF(fa, (const char*)&lds[2][0])
    CLUSTER(1, 0, fb0, fb1)
    CLUSTER(1, 1, fb2, fb3)
    CLUSTER(1, 2, fb4, fb5)
    CLUSTER(1, 3, fb6, fb7)
    // ---- kb=2: uses fa; prefetch fb <- buf3 ----
    WAITB
    STAGE(1, (t * PPT + 5) & PMASK);
    PREF(fb, (const char*)&lds[3][0])
    CLUSTER(2, 0, fa0, fa1)
    CLUSTER(2, 1, fa2, fa3)
    CLUSTER(2, 2, fa4, fa5)
    CLUSTER(2, 3, fa6, fa7)
    // ---- kb=3: uses fb; prefetch fa <- buf0 (next tile's kb=0) ----
    WAITB
    STAGE(2, (t * PPT + 6) & PMASK);
    PREF(fa, (const char*)&lds[0][0])
    CLUSTER(3, 0, fb0, fb1)
    CLUSTER(3, 1, fb2, fb3)
    CLUSTER(3, 2, fb4, fb5)
    CLUSTER(3, 3, fb6, fb7)
  }
  // ---- final epilogue for tile NTILES-1 ----
  {
    const int colb0p = (NTILES - 1) * NT;
    const bool dg = ((NTILES - 1) == tdiag);
    EPI(0, colb0p, dg);
    EPI(1, colb0p, dg);
    EPI(2, colb0p, dg);
    EPI(3, colb0p, dg);
  }
#undef WAITB
#undef PREF
#undef CLUSTER
#undef CLUSTERZ
#undef EPI

  // ---- cross-lane key max within each 16-lane group ------------------------
  #pragma unroll
  for (int m = 1; m <= 8; m <<= 1) {
    #pragma unroll
    for (int rf = 0; rf < 4; ++rf) {
      #pragma unroll
      for (int r = 0; r < 4; ++r) {
        const uint32_t ok =
            (uint32_t)__shfl_xor((int)rkey[rf][r], m, 64);
        rkey[rf][r] = rkey[rf][r] > ok ? rkey[rf][r] : ok;
      }
    }
  }
  if (c15 == 0) {
    #pragma unroll
    for (int rf = 0; rf < 4; ++rf) {
      #pragma unroll
      for (int r = 0; r < 4; ++r) {
        const int grow = rowbase + rf * 16 + hi4 + r;
        keys[cs * NROWS + grow] = rkey[rf][r];
      }
    }
  }
}

// ---------------- Kernel C1: combine splits, exact f32 distance + log -------
__global__ __launch_bounds__(256) void kdist(const float* __restrict__ in,
                                             const float* __restrict__ inv,
                                             const uint32_t* __restrict__ keys,
                                             float* __restrict__ partial) {
  __shared__ float acc4[4];
  const int lane = threadIdx.x & 63;
  const int wave = threadIdx.x >> 6;
  const int row = blockIdx.x * 4 + wave;
  uint32_t bk = 0u; int bs = 0;
  #pragma unroll
  for (int s = 0; s < CSPLIT; ++s) {
    const uint32_t k = keys[s * NROWS + row];
    if (k > bk) { bk = k; bs = s; }
  }
  const int bi = bs * COLS_PER_SPLIT + 2047 - (int)(bk & 2047u);
  const float ii = inv[row], jj = inv[bi];
  const float4* pi = (const float4*)(in + (size_t)row * DIM + lane * 8);
  const float4* pj = (const float4*)(in + (size_t)bi * DIM + lane * 8);
  const float4 a0 = pi[0], a1 = pi[1], b0 = pj[0], b1 = pj[1];
  float d, ss = 0.0f;
  d = a0.x*ii - b0.x*jj + 1e-8f; ss += d*d;
  d = a0.y*ii - b0.y*jj + 1e-8f; ss += d*d;
  d = a0.z*ii - b0.z*jj + 1e-8f; ss += d*d;
  d = a0.w*ii - b0.w*jj + 1e-8f; ss += d*d;
  d = a1.x*ii - b1.x*jj + 1e-8f; ss += d*d;
  d = a1.y*ii - b1.y*jj + 1e-8f; ss += d*d;
  d = a1.z*ii - b1.z*jj + 1e-8f; ss += d*d;
  d = a1.w*ii - b1.w*jj + 1e-8f; ss += d*d;
  #pragma unroll
  for (int m = 32; m >= 1; m >>= 1) ss += __shfl_xor(ss, m, 64);
  if (lane == 0) acc4[wave] = logf(sqrtf(ss) + 1e-8f);
  __syncthreads();
  if (threadIdx.x == 0)
    partial[blockIdx.x] = acc4[0] + acc4[1] + acc4[2] + acc4[3];
}

// ---------------- Kernel C2: final reduce -> loss ---------------------------
__global__ __launch_bounds__(256) void kfinal(const float* __restrict__ partial,
                                              float* __restrict__ out) {
  __shared__ float acc4[4];
  const int lane = threadIdx.x & 63;
  const int wave = threadIdx.x >> 6;
  float s = 0.0f;
  for (int i = threadIdx.x; i < NROWS / 4; i += 256) s += partial[i];
  #pragma unroll
  for (int m = 32; m >= 1; m >>= 1) s += __shfl_xor(s, m, 64);
  if (lane == 0) acc4[wave] = s;
  __syncthreads();
  if (threadIdx.x == 0)
    out[0] = -(acc4[0] + acc4[1] + acc4[2] + acc4[3]) * (1.0f / (float)NROWS);
}

extern "C" void kernel_launch(void* const* d_in, const int* in_sizes, int n_in,
                              void* d_out, int out_size, void* d_ws, size_t ws_size,
                              hipStream_t stream) {
  const float* in = (const float*)d_in[0];
  char* ws = (char*)d_ws;
  signed char* xq   = (signed char*)(ws);                  //  8,388,608 B
  float*       inv  = (float*)(ws + 8388608);              //     65,536 B
  uint32_t*    keys = (uint32_t*)(ws + 8454144);           //    524,288 B
  float*       part = (float*)(ws + 8978432);              //     16,384 B

  knorm<<<NROWS / 4, 256, 0, stream>>>(in, xq, inv);
  kdots<<<(NROWS / BM) * CSPLIT, 256, 0, stream>>>(xq, keys);
  kdist<<<NROWS / 4, 256, 0, stream>>>(in, inv, keys, part);
  kfinal<<<1, 256, 0, stream>>>(part, (float*)d_out);
}

// Round 17
// 160.141 us; speedup vs baseline: 1.7599x; 1.7599x over previous
//
#include <hip/hip_runtime.h>
#include <stdint.h>

#define NROWS 16384
#define DIM 512
#define CSPLIT 8
#define COLS_PER_SPLIT (NROWS / CSPLIT)   // 2048
#define BM 256                            // rows per block (4 waves x 64)
#define NT 64                             // cols per tile
#define BK 128                            // k per K-step
#define NTILES (COLS_PER_SPLIT / NT)      // 32
#define PPT (DIM / BK)                    // 4 K-steps per tile
#define NPHASE (NTILES * PPT)             // 128
#define PMASK (NPHASE - 1)

using i32x4 = __attribute__((ext_vector_type(4))) int;
using char8 = __attribute__((ext_vector_type(8))) signed char;

#define AS1 __attribute__((address_space(1)))
#define AS3 __attribute__((address_space(3)))

// ---------------- Kernel A: L2-normalize + FIXED-scale i8 quantize ----------
__global__ __launch_bounds__(256) void knorm(const float* __restrict__ in,
                                             signed char* __restrict__ xq,
                                             float* __restrict__ inv) {
  const int lane = threadIdx.x & 63;
  const int wave = threadIdx.x >> 6;
  const int row = blockIdx.x * 4 + wave;
  const float4* p = (const float4*)(in + (size_t)row * DIM + lane * 8);
  const float4 a = p[0], b = p[1];
  float ss = a.x*a.x + a.y*a.y + a.z*a.z + a.w*a.w
           + b.x*b.x + b.y*b.y + b.z*b.z + b.w*b.w;
  #pragma unroll
  for (int m = 32; m >= 1; m >>= 1) ss += __shfl_xor(ss, m, 64);
  const float iv = 1.0f / fmaxf(sqrtf(ss), 1e-8f);
  const float s508 = iv * 508.0f;
  char8 q;
  q[0] = (signed char)(int)rintf(fminf(fmaxf(a.x * s508, -127.f), 127.f));
  q[1] = (signed char)(int)rintf(fminf(fmaxf(a.y * s508, -127.f), 127.f));
  q[2] = (signed char)(int)rintf(fminf(fmaxf(a.z * s508, -127.f), 127.f));
  q[3] = (signed char)(int)rintf(fminf(fmaxf(a.w * s508, -127.f), 127.f));
  q[4] = (signed char)(int)rintf(fminf(fmaxf(b.x * s508, -127.f), 127.f));
  q[5] = (signed char)(int)rintf(fminf(fmaxf(b.y * s508, -127.f), 127.f));
  q[6] = (signed char)(int)rintf(fminf(fmaxf(b.z * s508, -127.f), 127.f));
  q[7] = (signed char)(int)rintf(fminf(fmaxf(b.w * s508, -127.f), 127.f));
  *(char8*)(xq + (size_t)row * DIM + lane * 8) = q;
  if (lane == 0) inv[row] = iv;
}

// ---------------- Kernel B: i8 Gram + fused integer argmax ------------------
// R10 + race-free cross-step prefetch:
//  * wave w stages bytes [w*2K,(w+1)*2K) of every buffer (own 2 loads);
//  * wave w's cluster q covers physical col-frag (w+q)&3, so cluster 0's
//    region is self-staged -> prefetchable under the PREVIOUS step's MFMAs
//    ordered by the wave's OWN vmcnt (no cross-wave race);
//  * +8 regs (pA/pB) only.
__global__ __launch_bounds__(256, 2) void kdots(const signed char* __restrict__ xq,
                                                uint32_t* __restrict__ keys) {
  const int tid  = threadIdx.x;
  const int lane = tid & 63;
  const int wave = tid >> 6;
  const int bx = blockIdx.x;
  const int cs = bx & (CSPLIT - 1);     // same-cs blocks land on same XCD (%8)
  const int rb = bx >> 3;
  const int rowbase  = rb * BM + wave * 64;
  const int colsplit = cs * COLS_PER_SPLIT;
  const int tdiag = ((rowbase >> 11) == cs) ? ((rowbase - colsplit) >> 6) : -1;
  const int c15 = lane & 15;
  const int hi4 = (lane >> 4) * 4;

  // rotated cluster->colfrag map (uniform per wave)
  const int qp0 = wave, qp1 = (wave + 1) & 3, qp2 = (wave + 2) & 3,
            qp3 = (wave + 3) & 3;
  const int o0 = qp0 * 2048, o1 = qp1 * 2048, o2 = qp2 * 2048, o3 = qp3 * 2048;

  __shared__ signed char lds[4][NT * BK];   // 4 x 8 KB

  // ---- A fragments in registers: 4 rowfrags x 8 kfrags(K=64) = 128 VGPR ----
  i32x4 areg[4][8];
  #pragma unroll
  for (int rf = 0; rf < 4; ++rf) {
    const signed char* ap =
        xq + (size_t)(rowbase + rf * 16 + c15) * DIM + ((lane >> 4) * 16);
    #pragma unroll
    for (int kf = 0; kf < 8; ++kf)
      areg[rf][kf] = *(const i32x4*)(ap + kf * 64);
  }

  uint32_t rkey[4][4];
  #pragma unroll
  for (int rf = 0; rf < 4; ++rf)
    #pragma unroll
    for (int r = 0; r < 4; ++r) rkey[rf][r] = 0u;

  i32x4 acc[4][4];   // acc[rf][q]: q = rotated cluster, colfrag = (wave+q)&3

  // stage wave's own 2 KB region of a buffer: 2 global_load_lds(16B)/lane
  auto STAGE = [&](int buf, int p) {
    const int tt = p >> 2, kb2 = p & 3;
    #pragma unroll
    for (int h = 0; h < 2; ++h) {
      const int u = wave * 128 + h * 64 + lane;
      const int col = u >> 3;
      const int k16 = u & 7;
      const signed char* g = xq + (size_t)(colsplit + tt * NT + col) * DIM
                           + kb2 * BK + ((k16 ^ (col & 7)) << 4);
      char* l = ((char*)&lds[buf][0]) + u * 16;
      __builtin_amdgcn_global_load_lds((AS1 const void*)g, (AS3 void*)l, 16, 0, 0);
    }
  };

  const int ro0 = c15 * 128 + (((lane >> 4) ^ (lane & 7)) << 4);
  const int ro1 = ro0 ^ 64;

  i32x4 pA, pB;   // cross-step prefetched first-cluster frags (+8 regs)

#define EPI(QI, QPV, COLB0P, DG)                                               \
  do {                                                                         \
    const uint32_t k0c =                                                       \
        0x80000000u + 2047u - (uint32_t)((COLB0P) + (QPV) * 16 + c15);         \
    _Pragma("unroll")                                                          \
    for (int rf = 0; rf < 4; ++rf) {                                           \
      _Pragma("unroll")                                                        \
      for (int r = 0; r < 4; ++r) {                                            \
        const int t1 = acc[rf][QI][r] >> 3;                                    \
        uint32_t key = ((uint32_t)t1 << 11) + k0c;                             \
        if ((DG) && rf == (QPV)) key = (c15 == hi4 + r) ? 0u : key;            \
        rkey[rf][r] = rkey[rf][r] > key ? rkey[rf][r] : key;                   \
      }                                                                        \
    }                                                                          \
  } while (0)

#define CLUSTER(KB, QI, BA, BB)                                                \
  __builtin_amdgcn_s_setprio(1);                                              \
  acc[0][QI] = __builtin_amdgcn_mfma_i32_16x16x64_i8(areg[0][(KB)*2], BA, acc[0][QI], 0,0,0);\
  acc[1][QI] = __builtin_amdgcn_mfma_i32_16x16x64_i8(areg[1][(KB)*2], BA, acc[1][QI], 0,0,0);\
  acc[2][QI] = __builtin_amdgcn_mfma_i32_16x16x64_i8(areg[2][(KB)*2], BA, acc[2][QI], 0,0,0);\
  acc[3][QI] = __builtin_amdgcn_mfma_i32_16x16x64_i8(areg[3][(KB)*2], BA, acc[3][QI], 0,0,0);\
  acc[0][QI] = __builtin_amdgcn_mfma_i32_16x16x64_i8(areg[0][(KB)*2+1], BB, acc[0][QI], 0,0,0);\
  acc[1][QI] = __builtin_amdgcn_mfma_i32_16x16x64_i8(areg[1][(KB)*2+1], BB, acc[1][QI], 0,0,0);\
  acc[2][QI] = __builtin_amdgcn_mfma_i32_16x16x64_i8(areg[2][(KB)*2+1], BB, acc[2][QI], 0,0,0);\
  acc[3][QI] = __builtin_amdgcn_mfma_i32_16x16x64_i8(areg[3][(KB)*2+1], BB, acc[3][QI], 0,0,0);\
  __builtin_amdgcn_s_setprio(0);

#define CLUSTERZ(QI, BA, BB)                                                   \
  __builtin_amdgcn_s_setprio(1);                                              \
  acc[0][QI] = __builtin_amdgcn_mfma_i32_16x16x64_i8(areg[0][0], BA, (i32x4){0,0,0,0}, 0,0,0);\
  acc[1][QI] = __builtin_amdgcn_mfma_i32_16x16x64_i8(areg[1][0], BA, (i32x4){0,0,0,0}, 0,0,0);\
  acc[2][QI] = __builtin_amdgcn_mfma_i32_16x16x64_i8(areg[2][0], BA, (i32x4){0,0,0,0}, 0,0,0);\
  acc[3][QI] = __builtin_amdgcn_mfma_i32_16x16x64_i8(areg[3][0], BA, (i32x4){0,0,0,0}, 0,0,0);\
  acc[0][QI] = __builtin_amdgcn_mfma_i32_16x16x64_i8(areg[0][1], BB, acc[0][QI], 0,0,0);\
  acc[1][QI] = __builtin_amdgcn_mfma_i32_16x16x64_i8(areg[1][1], BB, acc[1][QI], 0,0,0);\
  acc[2][QI] = __builtin_amdgcn_mfma_i32_16x16x64_i8(areg[2][1], BB, acc[2][QI], 0,0,0);\
  acc[3][QI] = __builtin_amdgcn_mfma_i32_16x16x64_i8(areg[3][1], BB, acc[3][QI], 0,0,0);\
  __builtin_amdgcn_s_setprio(0);

  __syncthreads();   // drains areg loads (vmcnt -> 0)
  STAGE(0, 0); STAGE(1, 1); STAGE(2, 2);   // depth-3 prologue: 6 own loads out
  asm volatile("s_waitcnt vmcnt(4)" ::: "memory");   // own phase-0 loads landed
  pA = *(const i32x4*)((const char*)&lds[0][0] + o0 + ro0);
  pB = *(const i32x4*)((const char*)&lds[0][0] + o0 + ro1);

  for (int t = 0; t < NTILES; ++t) {
    const int colb0p = (t - 1) * NT;
    const bool dg = ((t - 1) == tdiag);
    #pragma unroll
    for (int kb = 0; kb < PPT; ++kb) {
      asm volatile("s_waitcnt vmcnt(4)" ::: "memory"); // phase kb landed (all)
      __builtin_amdgcn_s_barrier();
      asm volatile("" ::: "memory");
      STAGE((kb + 3) & 3, (t * PPT + kb + 3) & PMASK);
      const char* base  = (const char*)&lds[kb & 3][0];
      const char* nbase = (const char*)&lds[(kb + 1) & 3][0];
      i32x4 c1a = *(const i32x4*)(base + o1 + ro0);
      i32x4 c1b = *(const i32x4*)(base + o1 + ro1);
      if (kb == 0) {
        if (t) EPI(0, qp0, colb0p, dg);
        CLUSTERZ(0, pA, pB)
      } else {
        CLUSTER(kb, 0, pA, pB)
      }
      i32x4 c2a = *(const i32x4*)(base + o2 + ro0);
      i32x4 c2b = *(const i32x4*)(base + o2 + ro1);
      if (kb == 0) {
        if (t) EPI(1, qp1, colb0p, dg);
        CLUSTERZ(1, c1a, c1b)
      } else {
        CLUSTER(kb, 1, c1a, c1b)
      }
      i32x4 c3a = *(const i32x4*)(base + o3 + ro0);
      i32x4 c3b = *(const i32x4*)(base + o3 + ro1);
      if (kb == 0) {
        if (t) EPI(2, qp2, colb0p, dg);
        CLUSTERZ(2, c2a, c2b)
      } else {
        CLUSTER(kb, 2, c2a, c2b)
      }
      // own phase-(kb+1) loads landed (issued 3 steps ago -> free wait);
      // prefetch next step's first-cluster frags from SELF-staged region.
      asm volatile("s_waitcnt vmcnt(4)" ::: "memory");
      pA = *(const i32x4*)(nbase + o0 + ro0);
      pB = *(const i32x4*)(nbase + o0 + ro1);
      if (kb == 0) {
        if (t) EPI(3, qp3, colb0p, dg);
        CLUSTERZ(3, c3a, c3b)
      } else {
        CLUSTER(kb, 3, c3a, c3b)
      }
    }
  }
  // ---- final epilogue for tile NTILES-1 ----
  {
    const int colb0p = (NTILES - 1) * NT;
    const bool dg = ((NTILES - 1) == tdiag);
    EPI(0, qp0, colb0p, dg);
    EPI(1, qp1, colb0p, dg);
    EPI(2, qp2, colb0p, dg);
    EPI(3, qp3, colb0p, dg);
  }
#undef CLUSTER
#undef CLUSTERZ
#undef EPI

  // ---- cross-lane key max within each 16-lane group ------------------------
  #pragma unroll
  for (int m = 1; m <= 8; m <<= 1) {
    #pragma unroll
    for (int rf = 0; rf < 4; ++rf) {
      #pragma unroll
      for (int r = 0; r < 4; ++r) {
        const uint32_t ok =
            (uint32_t)__shfl_xor((int)rkey[rf][r], m, 64);
        rkey[rf][r] = rkey[rf][r] > ok ? rkey[rf][r] : ok;
      }
    }
  }
  if (c15 == 0) {
    #pragma unroll
    for (int rf = 0; rf < 4; ++rf) {
      #pragma unroll
      for (int r = 0; r < 4; ++r) {
        const int grow = rowbase + rf * 16 + hi4 + r;
        keys[cs * NROWS + grow] = rkey[rf][r];
      }
    }
  }
}

// ---------------- Kernel C1: combine splits, exact f32 distance + log -------
__global__ __launch_bounds__(256) void kdist(const float* __restrict__ in,
                                             const float* __restrict__ inv,
                                             const uint32_t* __restrict__ keys,
                                             float* __restrict__ partial) {
  __shared__ float acc4[4];
  const int lane = threadIdx.x & 63;
  const int wave = threadIdx.x >> 6;
  const int row = blockIdx.x * 4 + wave;
  uint32_t bk = 0u; int bs = 0;
  #pragma unroll
  for (int s = 0; s < CSPLIT; ++s) {
    const uint32_t k = keys[s * NROWS + row];
    if (k > bk) { bk = k; bs = s; }
  }
  const int bi = bs * COLS_PER_SPLIT + 2047 - (int)(bk & 2047u);
  const float ii = inv[row], jj = inv[bi];
  const float4* pi = (const float4*)(in + (size_t)row * DIM + lane * 8);
  const float4* pj = (const float4*)(in + (size_t)bi * DIM + lane * 8);
  const float4 a0 = pi[0], a1 = pi[1], b0 = pj[0], b1 = pj[1];
  float d, ss = 0.0f;
  d = a0.x*ii - b0.x*jj + 1e-8f; ss += d*d;
  d = a0.y*ii - b0.y*jj + 1e-8f; ss += d*d;
  d = a0.z*ii - b0.z*jj + 1e-8f; ss += d*d;
  d = a0.w*ii - b0.w*jj + 1e-8f; ss += d*d;
  d = a1.x*ii - b1.x*jj + 1e-8f; ss += d*d;
  d = a1.y*ii - b1.y*jj + 1e-8f; ss += d*d;
  d = a1.z*ii - b1.z*jj + 1e-8f; ss += d*d;
  d = a1.w*ii - b1.w*jj + 1e-8f; ss += d*d;
  #pragma unroll
  for (int m = 32; m >= 1; m >>= 1) ss += __shfl_xor(ss, m, 64);
  if (lane == 0) acc4[wave] = logf(sqrtf(ss) + 1e-8f);
  __syncthreads();
  if (threadIdx.x == 0)
    partial[blockIdx.x] = acc4[0] + acc4[1] + acc4[2] + acc4[3];
}

// ---------------- Kernel C2: final reduce -> loss ---------------------------
__global__ __launch_bounds__(256) void kfinal(const float* __restrict__ partial,
                                              float* __restrict__ out) {
  __shared__ float acc4[4];
  const int lane = threadIdx.x & 63;
  const int wave = threadIdx.x >> 6;
  float s = 0.0f;
  for (int i = threadIdx.x; i < NROWS / 4; i += 256) s += partial[i];
  #pragma unroll
  for (int m = 32; m >= 1; m >>= 1) s += __shfl_xor(s, m, 64);
  if (lane == 0) acc4[wave] = s;
  __syncthreads();
  if (threadIdx.x == 0)
    out[0] = -(acc4[0] + acc4[1] + acc4[2] + acc4[3]) * (1.0f / (float)NROWS);
}

extern "C" void kernel_launch(void* const* d_in, const int* in_sizes, int n_in,
                              void* d_out, int out_size, void* d_ws, size_t ws_size,
                              hipStream_t stream) {
  const float* in = (const float*)d_in[0];
  char* ws = (char*)d_ws;
  signed char* xq   = (signed char*)(ws);                  //  8,388,608 B
  float*       inv  = (float*)(ws + 8388608);              //     65,536 B
  uint32_t*    keys = (uint32_t*)(ws + 8454144);           //    524,288 B
  float*       part = (float*)(ws + 8978432);              //     16,384 B

  knorm<<<NROWS / 4, 256, 0, stream>>>(in, xq, inv);
  kdots<<<(NROWS / BM) * CSPLIT, 256, 0, stream>>>(xq, keys);
  kdist<<<NROWS / 4, 256, 0, stream>>>(in, inv, keys, part);
  kfinal<<<1, 256, 0, stream>>>(part, (float*)d_out);
}

// Round 18
// 137.093 us; speedup vs baseline: 2.0557x; 1.1681x over previous
//
#include <hip/hip_runtime.h>
#include <stdint.h>

#define NROWS 16384
#define DIM 512
#define CSPLIT 8
#define COLS_PER_SPLIT (NROWS / CSPLIT)   // 2048
#define BM 256                            // rows per block (4 waves x 64)
#define NT 64                             // cols per tile
#define BK 128                            // k per K-step
#define NTILES (COLS_PER_SPLIT / NT)      // 32
#define PPT (DIM / BK)                    // 4 K-steps per tile
#define NPHASE (NTILES * PPT)             // 128

using i32x4 = __attribute__((ext_vector_type(4))) int;
using char8 = __attribute__((ext_vector_type(8))) signed char;

#define AS1 __attribute__((address_space(1)))
#define AS3 __attribute__((address_space(3)))

// ---------------- Kernel A: L2-normalize + FIXED-scale i8 quantize ----------
// q = round(clamp(x_norm * 508, -127, 127));  508 = 127/0.25.  The global
// scale is constant, so argmax over columns reduces to integer argmax of idot.
__global__ __launch_bounds__(256) void knorm(const float* __restrict__ in,
                                             signed char* __restrict__ xq,
                                             float* __restrict__ inv) {
  const int lane = threadIdx.x & 63;
  const int wave = threadIdx.x >> 6;
  const int row = blockIdx.x * 4 + wave;
  const float4* p = (const float4*)(in + (size_t)row * DIM + lane * 8);
  const float4 a = p[0], b = p[1];
  float ss = a.x*a.x + a.y*a.y + a.z*a.z + a.w*a.w
           + b.x*b.x + b.y*b.y + b.z*b.z + b.w*b.w;
  #pragma unroll
  for (int m = 32; m >= 1; m >>= 1) ss += __shfl_xor(ss, m, 64);
  const float iv = 1.0f / fmaxf(sqrtf(ss), 1e-8f);
  const float s508 = iv * 508.0f;
  char8 q;
  q[0] = (signed char)(int)rintf(fminf(fmaxf(a.x * s508, -127.f), 127.f));
  q[1] = (signed char)(int)rintf(fminf(fmaxf(a.y * s508, -127.f), 127.f));
  q[2] = (signed char)(int)rintf(fminf(fmaxf(a.z * s508, -127.f), 127.f));
  q[3] = (signed char)(int)rintf(fminf(fmaxf(a.w * s508, -127.f), 127.f));
  q[4] = (signed char)(int)rintf(fminf(fmaxf(b.x * s508, -127.f), 127.f));
  q[5] = (signed char)(int)rintf(fminf(fmaxf(b.y * s508, -127.f), 127.f));
  q[6] = (signed char)(int)rintf(fminf(fmaxf(b.z * s508, -127.f), 127.f));
  q[7] = (signed char)(int)rintf(fminf(fmaxf(b.w * s508, -127.f), 127.f));
  *(char8*)(xq + (size_t)row * DIM + lane * 8) = q;
  if (lane == 0) inv[row] = iv;
}

// ---------------- Kernel B: i8 Gram + fused integer argmax ------------------
// Best measured structure (R10): 4 waves x 64 rows, A register-resident
// (128 VGPR), 4 x 8 KB LDS buffers, depth-3 prefetch, counted vmcnt(4) + ONE
// barrier per K-step, cluster-pipelined compiler-scheduled LDS reads, setprio
// around MFMA clusters, integer packed keys (3 VALU/value), zero-C first
// K-step, prev-tile epilogue interleaved into kb=0's clusters.
__global__ __launch_bounds__(256, 2) void kdots(const signed char* __restrict__ xq,
                                                uint32_t* __restrict__ keys) {
  const int tid  = threadIdx.x;
  const int lane = tid & 63;
  const int wave = tid >> 6;
  const int bx = blockIdx.x;
  const int cs = bx & (CSPLIT - 1);     // same-cs blocks land on same XCD (%8)
  const int rb = bx >> 3;
  const int rowbase  = rb * BM + wave * 64;
  const int colsplit = cs * COLS_PER_SPLIT;
  // the one tile (per wave) containing diagonal elements, or -1
  const int tdiag = ((rowbase >> 11) == cs) ? ((rowbase - colsplit) >> 6) : -1;
  const int c15 = lane & 15;
  const int hi4 = (lane >> 4) * 4;

  __shared__ signed char lds[4][NT * BK];   // 4 x 8 KB

  // ---- A fragments in registers: 4 rowfrags x 8 kfrags(K=64) = 128 VGPR ----
  i32x4 areg[4][8];
  #pragma unroll
  for (int rf = 0; rf < 4; ++rf) {
    const signed char* ap =
        xq + (size_t)(rowbase + rf * 16 + c15) * DIM + ((lane >> 4) * 16);
    #pragma unroll
    for (int kf = 0; kf < 8; ++kf)
      areg[rf][kf] = *(const i32x4*)(ap + kf * 64);
  }

  uint32_t rkey[4][4];
  #pragma unroll
  for (int rf = 0; rf < 4; ++rf)
    #pragma unroll
    for (int r = 0; r < 4; ++r) rkey[rf][r] = 0u;

  i32x4 acc[4][4];   // written by zero-C clusters each tile; read next tile

  // stage one 8 KB buffer: 2 global_load_lds(16B) per thread.
  // LDS layout [col][8 x 16B k-chunks], source k-chunk pre-swizzled k16^(col&7).
  auto STAGE = [&](int buf, int p) {
    const int tt = p >> 2, kb2 = p & 3;
    #pragma unroll
    for (int h = 0; h < 2; ++h) {
      const int u = h * 256 + tid;
      const int col = u >> 3;
      const int k16 = u & 7;
      const signed char* g = xq + (size_t)(colsplit + tt * NT + col) * DIM
                           + kb2 * BK + ((k16 ^ (col & 7)) << 4);
      char* l = ((char*)&lds[buf][0]) + u * 16;
      __builtin_amdgcn_global_load_lds((AS1 const void*)g, (AS3 void*)l, 16, 0, 0);
    }
  };

  __syncthreads();   // drains areg loads (vmcnt -> 0)
  STAGE(0, 0); STAGE(1, 1); STAGE(2, 2);   // depth-3 prologue: 6 outstanding

  // ds_read offsets: cf*2048 + c15*128 + ((kk*4+hi)^(c15&7))*16; kk=1 = ^64
  const int ro0 = c15 * 128 + (((lane >> 4) ^ (lane & 7)) << 4);
  const int ro1 = ro0 ^ 64;

// integer packed-key epilogue chunk for prev tile's acc[*][Q] (Q literal)
#define EPI(Q, COLB0P, DG)                                                     \
  do {                                                                         \
    const uint32_t k0c =                                                       \
        0x80000000u + 2047u - (uint32_t)((COLB0P) + (Q) * 16 + c15);           \
    _Pragma("unroll")                                                          \
    for (int rf = 0; rf < 4; ++rf) {                                           \
      _Pragma("unroll")                                                        \
      for (int r = 0; r < 4; ++r) {                                            \
        const int t1 = acc[rf][Q][r] >> 3;                                     \
        uint32_t key = ((uint32_t)t1 << 11) + k0c;                             \
        if (rf == (Q) && (DG)) key = (c15 == hi4 + r) ? 0u : key;              \
        rkey[rf][r] = rkey[rf][r] > key ? rkey[rf][r] : key;                   \
      }                                                                        \
    }                                                                          \
  } while (0)

#define CLUSTER(Q, BA, BB)                                                     \
  __builtin_amdgcn_s_setprio(1);                                              \
  acc[0][Q] = __builtin_amdgcn_mfma_i32_16x16x64_i8(a0, BA, acc[0][Q], 0,0,0);\
  acc[1][Q] = __builtin_amdgcn_mfma_i32_16x16x64_i8(a1, BA, acc[1][Q], 0,0,0);\
  acc[2][Q] = __builtin_amdgcn_mfma_i32_16x16x64_i8(a2, BA, acc[2][Q], 0,0,0);\
  acc[3][Q] = __builtin_amdgcn_mfma_i32_16x16x64_i8(a3, BA, acc[3][Q], 0,0,0);\
  acc[0][Q] = __builtin_amdgcn_mfma_i32_16x16x64_i8(a4, BB, acc[0][Q], 0,0,0);\
  acc[1][Q] = __builtin_amdgcn_mfma_i32_16x16x64_i8(a5, BB, acc[1][Q], 0,0,0);\
  acc[2][Q] = __builtin_amdgcn_mfma_i32_16x16x64_i8(a6, BB, acc[2][Q], 0,0,0);\
  acc[3][Q] = __builtin_amdgcn_mfma_i32_16x16x64_i8(a7, BB, acc[3][Q], 0,0,0);\
  __builtin_amdgcn_s_setprio(0);

#define CLUSTERZ(Q, BA, BB)                                                    \
  __builtin_amdgcn_s_setprio(1);                                              \
  acc[0][Q] = __builtin_amdgcn_mfma_i32_16x16x64_i8(a0, BA, (i32x4){0,0,0,0}, 0,0,0);\
  acc[1][Q] = __builtin_amdgcn_mfma_i32_16x16x64_i8(a1, BA, (i32x4){0,0,0,0}, 0,0,0);\
  acc[2][Q] = __builtin_amdgcn_mfma_i32_16x16x64_i8(a2, BA, (i32x4){0,0,0,0}, 0,0,0);\
  acc[3][Q] = __builtin_amdgcn_mfma_i32_16x16x64_i8(a3, BA, (i32x4){0,0,0,0}, 0,0,0);\
  acc[0][Q] = __builtin_amdgcn_mfma_i32_16x16x64_i8(a4, BB, acc[0][Q], 0,0,0);\
  acc[1][Q] = __builtin_amdgcn_mfma_i32_16x16x64_i8(a5, BB, acc[1][Q], 0,0,0);\
  acc[2][Q] = __builtin_amdgcn_mfma_i32_16x16x64_i8(a6, BB, acc[2][Q], 0,0,0);\
  acc[3][Q] = __builtin_amdgcn_mfma_i32_16x16x64_i8(a7, BB, acc[3][Q], 0,0,0);\
  __builtin_amdgcn_s_setprio(0);

  for (int t = 0; t < NTILES; ++t) {
    const int colb0p = (t - 1) * NT;
    const bool dg = ((t - 1) == tdiag);
    // ---- K-step kb=0: zero-C clusters + interleaved prev-tile epilogue ----
    asm volatile("s_waitcnt vmcnt(4)" ::: "memory");
    __builtin_amdgcn_s_barrier();
    asm volatile("" ::: "memory");
    STAGE(3, (t * PPT + 3) & (NPHASE - 1));
    {
      const char* base = (const char*)&lds[0][0];
      const i32x4 a0 = areg[0][0], a1 = areg[1][0];
      const i32x4 a2 = areg[2][0], a3 = areg[3][0];
      const i32x4 a4 = areg[0][1], a5 = areg[1][1];
      const i32x4 a6 = areg[2][1], a7 = areg[3][1];
      i32x4 b0a = *(const i32x4*)(base + ro0);
      i32x4 b0b = *(const i32x4*)(base + ro1);
      i32x4 b1a = *(const i32x4*)(base + 2048 + ro0);
      i32x4 b1b = *(const i32x4*)(base + 2048 + ro1);
      if (t) EPI(0, colb0p, dg);
      CLUSTERZ(0, b0a, b0b)
      b0a = *(const i32x4*)(base + 4096 + ro0);
      b0b = *(const i32x4*)(base + 4096 + ro1);
      if (t) EPI(1, colb0p, dg);
      CLUSTERZ(1, b1a, b1b)
      b1a = *(const i32x4*)(base + 6144 + ro0);
      b1b = *(const i32x4*)(base + 6144 + ro1);
      if (t) EPI(2, colb0p, dg);
      CLUSTERZ(2, b0a, b0b)
      if (t) EPI(3, colb0p, dg);
      CLUSTERZ(3, b1a, b1b)
    }
    // ---- K-steps kb=1..3: accumulating clusters ----
    #pragma unroll
    for (int kb = 1; kb < PPT; ++kb) {
      asm volatile("s_waitcnt vmcnt(4)" ::: "memory");
      __builtin_amdgcn_s_barrier();
      asm volatile("" ::: "memory");
      STAGE((kb + 3) & 3, (t * PPT + kb + 3) & (NPHASE - 1));
      const char* base = (const char*)&lds[kb & 3][0];
      const i32x4 a0 = areg[0][kb*2],   a1 = areg[1][kb*2];
      const i32x4 a2 = areg[2][kb*2],   a3 = areg[3][kb*2];
      const i32x4 a4 = areg[0][kb*2+1], a5 = areg[1][kb*2+1];
      const i32x4 a6 = areg[2][kb*2+1], a7 = areg[3][kb*2+1];
      i32x4 b0a = *(const i32x4*)(base + ro0);
      i32x4 b0b = *(const i32x4*)(base + ro1);
      i32x4 b1a = *(const i32x4*)(base + 2048 + ro0);
      i32x4 b1b = *(const i32x4*)(base + 2048 + ro1);
      CLUSTER(0, b0a, b0b)
      b0a = *(const i32x4*)(base + 4096 + ro0);
      b0b = *(const i32x4*)(base + 4096 + ro1);
      CLUSTER(1, b1a, b1b)
      b1a = *(const i32x4*)(base + 6144 + ro0);
      b1b = *(const i32x4*)(base + 6144 + ro1);
      CLUSTER(2, b0a, b0b)
      CLUSTER(3, b1a, b1b)
    }
  }
  // ---- final epilogue for tile NTILES-1 ----
  {
    const int colb0p = (NTILES - 1) * NT;
    const bool dg = ((NTILES - 1) == tdiag);
    EPI(0, colb0p, dg);
    EPI(1, colb0p, dg);
    EPI(2, colb0p, dg);
    EPI(3, colb0p, dg);
  }
#undef CLUSTER
#undef CLUSTERZ
#undef EPI

  // ---- cross-lane key max within each 16-lane group ------------------------
  #pragma unroll
  for (int m = 1; m <= 8; m <<= 1) {
    #pragma unroll
    for (int rf = 0; rf < 4; ++rf) {
      #pragma unroll
      for (int r = 0; r < 4; ++r) {
        const uint32_t ok =
            (uint32_t)__shfl_xor((int)rkey[rf][r], m, 64);
        rkey[rf][r] = rkey[rf][r] > ok ? rkey[rf][r] : ok;
      }
    }
  }
  if (c15 == 0) {
    #pragma unroll
    for (int rf = 0; rf < 4; ++rf) {
      #pragma unroll
      for (int r = 0; r < 4; ++r) {
        const int grow = rowbase + rf * 16 + hi4 + r;
        keys[cs * NROWS + grow] = rkey[rf][r];
      }
    }
  }
}

// ---------------- Kernel C1: combine splits, exact f32 distance + log -------
__global__ __launch_bounds__(256) void kdist(const float* __restrict__ in,
                                             const float* __restrict__ inv,
                                             const uint32_t* __restrict__ keys,
                                             float* __restrict__ partial) {
  __shared__ float acc4[4];
  const int lane = threadIdx.x & 63;
  const int wave = threadIdx.x >> 6;
  const int row = blockIdx.x * 4 + wave;
  uint32_t bk = 0u; int bs = 0;
  #pragma unroll
  for (int s = 0; s < CSPLIT; ++s) {
    const uint32_t k = keys[s * NROWS + row];
    if (k > bk) { bk = k; bs = s; }
  }
  const int bi = bs * COLS_PER_SPLIT + 2047 - (int)(bk & 2047u);
  const float ii = inv[row], jj = inv[bi];
  const float4* pi = (const float4*)(in + (size_t)row * DIM + lane * 8);
  const float4* pj = (const float4*)(in + (size_t)bi * DIM + lane * 8);
  const float4 a0 = pi[0], a1 = pi[1], b0 = pj[0], b1 = pj[1];
  float d, ss = 0.0f;
  d = a0.x*ii - b0.x*jj + 1e-8f; ss += d*d;
  d = a0.y*ii - b0.y*jj + 1e-8f; ss += d*d;
  d = a0.z*ii - b0.z*jj + 1e-8f; ss += d*d;
  d = a0.w*ii - b0.w*jj + 1e-8f; ss += d*d;
  d = a1.x*ii - b1.x*jj + 1e-8f; ss += d*d;
  d = a1.y*ii - b1.y*jj + 1e-8f; ss += d*d;
  d = a1.z*ii - b1.z*jj + 1e-8f; ss += d*d;
  d = a1.w*ii - b1.w*jj + 1e-8f; ss += d*d;
  #pragma unroll
  for (int m = 32; m >= 1; m >>= 1) ss += __shfl_xor(ss, m, 64);
  if (lane == 0) acc4[wave] = logf(sqrtf(ss) + 1e-8f);
  __syncthreads();
  if (threadIdx.x == 0)
    partial[blockIdx.x] = acc4[0] + acc4[1] + acc4[2] + acc4[3];
}

// ---------------- Kernel C2: final reduce -> loss ---------------------------
__global__ __launch_bounds__(256) void kfinal(const float* __restrict__ partial,
                                              float* __restrict__ out) {
  __shared__ float acc4[4];
  const int lane = threadIdx.x & 63;
  const int wave = threadIdx.x >> 6;
  float s = 0.0f;
  for (int i = threadIdx.x; i < NROWS / 4; i += 256) s += partial[i];
  #pragma unroll
  for (int m = 32; m >= 1; m >>= 1) s += __shfl_xor(s, m, 64);
  if (lane == 0) acc4[wave] = s;
  __syncthreads();
  if (threadIdx.x == 0)
    out[0] = -(acc4[0] + acc4[1] + acc4[2] + acc4[3]) * (1.0f / (float)NROWS);
}

extern "C" void kernel_launch(void* const* d_in, const int* in_sizes, int n_in,
                              void* d_out, int out_size, void* d_ws, size_t ws_size,
                              hipStream_t stream) {
  const float* in = (const float*)d_in[0];
  char* ws = (char*)d_ws;
  signed char* xq   = (signed char*)(ws);                  //  8,388,608 B
  float*       inv  = (float*)(ws + 8388608);              //     65,536 B
  uint32_t*    keys = (uint32_t*)(ws + 8454144);           //    524,288 B
  float*       part = (float*)(ws + 8978432);              //     16,384 B

  knorm<<<NROWS / 4, 256, 0, stream>>>(in, xq, inv);
  kdots<<<(NROWS / BM) * CSPLIT, 256, 0, stream>>>(xq, keys);
  kdist<<<NROWS / 4, 256, 0, stream>>>(in, inv, keys, part);
  kfinal<<<1, 256, 0, stream>>>(part, (float*)d_out);
}